// Round 1
// baseline (1179.508 us; speedup 1.0000x reference)
//
#include <hip/hip_runtime.h>
#include <hip/hip_bf16.h>

#define N_NODES 50000
#define N_EDGES 800000
#define FEATS 128
#define HIDDEN 64

// ---------------------------------------------------------------------------
// deg[dst] += 1 over all edges
__global__ __launch_bounds__(256) void deg_kernel(const int* __restrict__ dst,
                                                  float* __restrict__ deg, int E) {
    int i = blockIdx.x * 256 + threadIdx.x;
    if (i < E) atomicAdd(&deg[dst[i]], 1.0f);
}

// isq[i] = rsqrt(max(deg[i], 1))   (in place over deg buffer)
__global__ __launch_bounds__(256) void isq_kernel(float* __restrict__ deg, int N) {
    int i = blockIdx.x * 256 + threadIdx.x;
    if (i < N) deg[i] = rsqrtf(fmaxf(deg[i], 1.0f));
}

// ---------------------------------------------------------------------------
// h0 = relu(x @ W1^T + b1)   x:[N,128] W1:[64,128] b1:[64] -> out:[N,64]
// thread = (node, j-quarter): 16 outputs/thread, x row in 128 VGPRs,
// weights in LDS read as wave-broadcast float4 (conflict-free).
__global__ __launch_bounds__(256) void layer1_kernel(const float* __restrict__ x,
                                                     const float* __restrict__ W1,
                                                     const float* __restrict__ b1,
                                                     float* __restrict__ out, int N) {
    __shared__ float sW[64 * 128];
    __shared__ float sb[64];
    for (int i = threadIdx.x; i < 64 * 128; i += 256) sW[i] = W1[i];
    if (threadIdx.x < 64) sb[threadIdx.x] = b1[threadIdx.x];
    __syncthreads();

    int t = blockIdx.x * 256 + threadIdx.x;
    int n = t >> 2, jq = t & 3;
    if (n >= N) return;

    float xr[128];
    const float4* x4 = (const float4*)(x + (size_t)n * 128);
#pragma unroll
    for (int i = 0; i < 32; i++) {
        float4 v = x4[i];
        xr[4 * i] = v.x; xr[4 * i + 1] = v.y; xr[4 * i + 2] = v.z; xr[4 * i + 3] = v.w;
    }

    for (int jj = 0; jj < 16; jj++) {
        int j = jq * 16 + jj;
        const float4* wr = (const float4*)(sW + j * 128);
        float a0 = 0.f, a1 = 0.f, a2 = 0.f, a3 = 0.f;
#pragma unroll
        for (int i = 0; i < 32; i++) {
            float4 w = wr[i];
            a0 += xr[4 * i] * w.x;
            a1 += xr[4 * i + 1] * w.y;
            a2 += xr[4 * i + 2] * w.z;
            a3 += xr[4 * i + 3] * w.w;
        }
        float s = (a0 + a1) + (a2 + a3) + sb[j];
        out[(size_t)n * 64 + j] = fmaxf(s, 0.f);
    }
}

// ---------------------------------------------------------------------------
// conv[dst] += h[src] * isq[src]*isq[dst]
// wave per edge, lane = feature: coalesced 256B gather + coalesced 256B atomic.
__global__ __launch_bounds__(256) void conv_kernel(const float* __restrict__ hin,
                                                   const int* __restrict__ src,
                                                   const int* __restrict__ dst,
                                                   const float* __restrict__ isq,
                                                   float* __restrict__ out, int E) {
    int wave = (blockIdx.x * 256 + threadIdx.x) >> 6;
    int lane = threadIdx.x & 63;
    int nwaves = (gridDim.x * 256) >> 6;
    for (int e = wave; e < E; e += nwaves) {
        int s = src[e];
        int d = dst[e];
        float coef = isq[s] * isq[d];
        float v = hin[(size_t)s * 64 + lane] * coef;
        atomicAdd(out + (size_t)d * 64 + lane, v);
    }
}

// ---------------------------------------------------------------------------
// out = relu( [h, conv] @ W^T + (h@Aa^T)*(h@Ab^T) )
// W:[64,128] Aa,Ab:[64,64]  thread = (node, j-quarter), rows in registers.
__global__ __launch_bounds__(256) void dense_block_kernel(const float* __restrict__ hin,
                                                          const float* __restrict__ conv,
                                                          const float* __restrict__ W,
                                                          const float* __restrict__ Aa,
                                                          const float* __restrict__ Ab,
                                                          float* __restrict__ out, int N) {
    __shared__ float sW[64 * 128];
    __shared__ float sAa[64 * 64];
    __shared__ float sAb[64 * 64];
    for (int i = threadIdx.x; i < 64 * 128; i += 256) sW[i] = W[i];
    for (int i = threadIdx.x; i < 64 * 64; i += 256) {
        sAa[i] = Aa[i];
        sAb[i] = Ab[i];
    }
    __syncthreads();

    int t = blockIdx.x * 256 + threadIdx.x;
    int n = t >> 2, jq = t & 3;
    if (n >= N) return;

    float hr[64], cr[64];
    const float4* h4 = (const float4*)(hin + (size_t)n * 64);
    const float4* c4 = (const float4*)(conv + (size_t)n * 64);
#pragma unroll
    for (int i = 0; i < 16; i++) {
        float4 v = h4[i];
        hr[4 * i] = v.x; hr[4 * i + 1] = v.y; hr[4 * i + 2] = v.z; hr[4 * i + 3] = v.w;
        float4 u = c4[i];
        cr[4 * i] = u.x; cr[4 * i + 1] = u.y; cr[4 * i + 2] = u.z; cr[4 * i + 3] = u.w;
    }

    for (int jj = 0; jj < 16; jj++) {
        int j = jq * 16 + jj;
        const float4* wrh = (const float4*)(sW + j * 128);       // k in [0,64)   vs h
        const float4* wrc = wrh + 16;                             // k in [64,128) vs conv
        const float4* ar = (const float4*)(sAa + j * 64);
        const float4* br = (const float4*)(sAb + j * 64);
        float w0 = 0.f, w1 = 0.f, w2 = 0.f, w3 = 0.f;
        float p0 = 0.f, p1 = 0.f, q0 = 0.f, q1 = 0.f;
#pragma unroll
        for (int i = 0; i < 16; i++) {
            float4 w = wrh[i];
            w0 += hr[4 * i] * w.x; w1 += hr[4 * i + 1] * w.y;
            w2 += hr[4 * i + 2] * w.z; w3 += hr[4 * i + 3] * w.w;
            float4 u = wrc[i];
            w0 += cr[4 * i] * u.x; w1 += cr[4 * i + 1] * u.y;
            w2 += cr[4 * i + 2] * u.z; w3 += cr[4 * i + 3] * u.w;
            float4 a = ar[i];
            p0 += hr[4 * i] * a.x; p1 += hr[4 * i + 1] * a.y;
            p0 += hr[4 * i + 2] * a.z; p1 += hr[4 * i + 3] * a.w;
            float4 b = br[i];
            q0 += hr[4 * i] * b.x; q1 += hr[4 * i + 1] * b.y;
            q0 += hr[4 * i + 2] * b.z; q1 += hr[4 * i + 3] * b.w;
        }
        float lin = (w0 + w1) + (w2 + w3);
        float s = lin + (p0 + p1) * (q0 + q1);
        out[(size_t)n * 64 + j] = fmaxf(s, 0.f);
    }
}

// ---------------------------------------------------------------------------
extern "C" void kernel_launch(void* const* d_in, const int* in_sizes, int n_in,
                              void* d_out, int out_size, void* d_ws, size_t ws_size,
                              hipStream_t stream) {
    const float* x = (const float*)d_in[0];
    const int* edges = (const int*)d_in[1];
    const float* W1 = (const float*)d_in[2];
    const float* b1 = (const float*)d_in[3];
    const float* W2 = (const float*)d_in[4];
    const float* A2a = (const float*)d_in[5];
    const float* A2b = (const float*)d_in[6];
    const float* W3 = (const float*)d_in[7];
    const float* A3a = (const float*)d_in[8];
    const float* A3b = (const float*)d_in[9];
    const float* W4 = (const float*)d_in[10];
    const float* A4a = (const float*)d_in[11];
    const float* A4b = (const float*)d_in[12];
    float* out = (float*)d_out;

    const int* src = edges;            // edges[0, :]
    const int* dst = edges + N_EDGES;  // edges[1, :]

    // workspace layout (floats)
    float* deg = (float*)d_ws;               // 50048 floats (isq in place)
    float* bufA = deg + 50048;               // [N,64]
    float* bufC = bufA + (size_t)N_NODES * 64;  // conv scratch
    float* bufB = bufC + (size_t)N_NODES * 64;

    const size_t rowBytes = (size_t)N_NODES * 64 * sizeof(float);

    // degree -> inv_sqrt (edges are fixed; one pass serves all 3 convs)
    hipMemsetAsync(deg, 0, N_NODES * sizeof(float), stream);
    deg_kernel<<<(N_EDGES + 255) / 256, 256, 0, stream>>>(dst, deg, N_EDGES);
    isq_kernel<<<(N_NODES + 255) / 256, 256, 0, stream>>>(deg, N_NODES);
    const float* isq = deg;

    // layer 1
    {
        int threads = N_NODES * 4;
        layer1_kernel<<<(threads + 255) / 256, 256, 0, stream>>>(x, W1, b1, bufA, N_NODES);
    }

    int convBlocks = 2048;
    int denseBlocks = (N_NODES * 4 + 255) / 256;

    // block 2: bufA -> bufB
    hipMemsetAsync(bufC, 0, rowBytes, stream);
    conv_kernel<<<convBlocks, 256, 0, stream>>>(bufA, src, dst, isq, bufC, N_EDGES);
    dense_block_kernel<<<denseBlocks, 256, 0, stream>>>(bufA, bufC, W2, A2a, A2b, bufB, N_NODES);

    // block 3: bufB -> bufA
    hipMemsetAsync(bufC, 0, rowBytes, stream);
    conv_kernel<<<convBlocks, 256, 0, stream>>>(bufB, src, dst, isq, bufC, N_EDGES);
    dense_block_kernel<<<denseBlocks, 256, 0, stream>>>(bufB, bufC, W3, A3a, A3b, bufA, N_NODES);

    // block 4: bufA -> d_out
    hipMemsetAsync(bufC, 0, rowBytes, stream);
    conv_kernel<<<convBlocks, 256, 0, stream>>>(bufA, src, dst, isq, bufC, N_EDGES);
    dense_block_kernel<<<denseBlocks, 256, 0, stream>>>(bufA, bufC, W4, A4a, A4b, out, N_NODES);
}

// Round 2
// 380.574 us; speedup vs baseline: 3.0993x; 3.0993x over previous
//
#include <hip/hip_runtime.h>
#include <hip/hip_bf16.h>

#define N_NODES 50000
#define N_EDGES 800000
#define NTILES 3125        // N_NODES / 16
#define SCAN_NB 196        // ceil(N_NODES / 256)
#define W_TOTAL 57344      // packed bf16 weight elements

typedef __attribute__((ext_vector_type(8))) short bf16x8;   // 8 bf16 = 4 VGPRs (MFMA A/B frag)
typedef __attribute__((ext_vector_type(4))) float f32x4;    // MFMA C/D frag

__device__ inline float bf2f(unsigned short u) {
    return __uint_as_float(((unsigned int)u) << 16);
}
__device__ inline unsigned short f2bf(float f) {  // round-to-nearest-even
    unsigned int x = __float_as_uint(f);
    unsigned int r = (x + 0x7FFF + ((x >> 16) & 1)) >> 16;
    return (unsigned short)r;
}

struct __align__(8) Rec { int s; float c; };

// ---------------------------------------------------------------------------
// CSR build: degree count
__global__ __launch_bounds__(256) void count_kernel(const int* __restrict__ dst,
                                                    int* __restrict__ degi) {
    int e = blockIdx.x * 256 + threadIdx.x;
    if (e < N_EDGES) atomicAdd(&degi[dst[e]], 1);
}

// scan phase 1: per-256-chunk inclusive scan + chunk totals; also isq = rsqrt(max(deg,1))
__global__ __launch_bounds__(256) void scan1_kernel(const int* __restrict__ degi,
                                                    int* __restrict__ incl,
                                                    int* __restrict__ partial,
                                                    float* __restrict__ isq) {
    __shared__ int s[256];
    int gid = blockIdx.x * 256 + threadIdx.x;
    int v = (gid < N_NODES) ? degi[gid] : 0;
    if (gid < N_NODES) isq[gid] = rsqrtf(fmaxf((float)v, 1.0f));
    s[threadIdx.x] = v;
    __syncthreads();
    for (int off = 1; off < 256; off <<= 1) {
        int t = (threadIdx.x >= off) ? s[threadIdx.x - off] : 0;
        __syncthreads();
        s[threadIdx.x] += t;
        __syncthreads();
    }
    if (gid < N_NODES) incl[gid] = s[threadIdx.x];
    if (threadIdx.x == 255) partial[blockIdx.x] = s[255];
}

// scan phase 2: exclusive scan of the chunk totals (in place), one block
__global__ __launch_bounds__(256) void scan2_kernel(int* __restrict__ partial) {
    __shared__ int s[256];
    int v = (threadIdx.x < SCAN_NB) ? partial[threadIdx.x] : 0;
    s[threadIdx.x] = v;
    __syncthreads();
    for (int off = 1; off < 256; off <<= 1) {
        int t = (threadIdx.x >= off) ? s[threadIdx.x - off] : 0;
        __syncthreads();
        s[threadIdx.x] += t;
        __syncthreads();
    }
    if (threadIdx.x < SCAN_NB) partial[threadIdx.x] = s[threadIdx.x] - v;  // exclusive
}

// scan phase 3: rowptr (exclusive) + cursor copy
__global__ __launch_bounds__(256) void scan3_kernel(const int* __restrict__ incl,
                                                    const int* __restrict__ partial,
                                                    const int* __restrict__ degi,
                                                    int* __restrict__ rowptr,
                                                    int* __restrict__ cursor) {
    int gid = blockIdx.x * 256 + threadIdx.x;
    if (gid < N_NODES) {
        int excl = partial[blockIdx.x] + incl[gid] - degi[gid];
        rowptr[gid] = excl;
        cursor[gid] = excl;
    }
    if (gid == 0) rowptr[N_NODES] = N_EDGES;
}

// scatter edges into CSR order; precompute coef = isq[src]*isq[dst]
__global__ __launch_bounds__(256) void scatter_kernel(const int* __restrict__ src,
                                                      const int* __restrict__ dst,
                                                      const float* __restrict__ isq,
                                                      int* __restrict__ cursor,
                                                      Rec* __restrict__ rec) {
    int e = blockIdx.x * 256 + threadIdx.x;
    if (e < N_EDGES) {
        int d = dst[e], s = src[e];
        int pos = atomicAdd(&cursor[d], 1);
        Rec r;
        r.s = s;
        r.c = isq[s] * isq[d];
        rec[pos] = r;
    }
}

// ---------------------------------------------------------------------------
// pack all weights to bf16 in one kernel (flat offsets, compile-time layout)
__global__ __launch_bounds__(256) void pack_w_kernel(const float* W1, const float* W2,
                                                     const float* A2a, const float* A2b,
                                                     const float* W3, const float* A3a,
                                                     const float* A3b, const float* W4,
                                                     const float* A4a, const float* A4b,
                                                     unsigned short* __restrict__ wp) {
    int i = blockIdx.x * 256 + threadIdx.x;
    if (i >= W_TOTAL) return;
    float v;
    if (i < 8192)       v = W1[i];
    else if (i < 16384) v = W2[i - 8192];
    else if (i < 20480) v = A2a[i - 16384];
    else if (i < 24576) v = A2b[i - 20480];
    else if (i < 32768) v = W3[i - 24576];
    else if (i < 36864) v = A3a[i - 32768];
    else if (i < 40960) v = A3b[i - 36864];
    else if (i < 49152) v = W4[i - 40960];
    else if (i < 53248) v = A4a[i - 49152];
    else                v = A4b[i - 53248];
    wp[i] = f2bf(v);
}

// ---------------------------------------------------------------------------
// layer1: out[n,j] = relu(sum_k x[n,k]*W1[j,k] + b1[j])   via 16x16x32 bf16 MFMA
// wave = one 16-node tile; A from x (fp32->bf16 on the fly), B from packed W1 bf16.
__global__ __launch_bounds__(256) void layer1_mfma(const float* __restrict__ x,
                                                   const unsigned short* __restrict__ w1p,
                                                   const float* __restrict__ b1,
                                                   unsigned short* __restrict__ out) {
    int wave = (blockIdx.x * 256 + threadIdx.x) >> 6;
    if (wave >= NTILES) return;
    int lane = threadIdx.x & 63;
    int r16 = lane & 15, quad = lane >> 4;
    int base = wave * 16;

    // A-frags: lane holds x[base+r16][kb*32 + quad*8 + 0..7]
    bf16x8 a[4];
    const float* xr = x + (size_t)(base + r16) * 128 + quad * 8;
#pragma unroll
    for (int kb = 0; kb < 4; kb++) {
        float4 f0 = *(const float4*)(xr + kb * 32);
        float4 f1 = *(const float4*)(xr + kb * 32 + 4);
        bf16x8 v;
        v[0] = (short)f2bf(f0.x); v[1] = (short)f2bf(f0.y);
        v[2] = (short)f2bf(f0.z); v[3] = (short)f2bf(f0.w);
        v[4] = (short)f2bf(f1.x); v[5] = (short)f2bf(f1.y);
        v[6] = (short)f2bf(f1.z); v[7] = (short)f2bf(f1.w);
        a[kb] = v;
    }

#pragma unroll
    for (int jt = 0; jt < 4; jt++) {
        f32x4 acc = {0.f, 0.f, 0.f, 0.f};
        // B-frag: lane holds W1[jt*16+r16][kb*32 + quad*8 + 0..7] (bf16, 16B load)
        const unsigned short* wr = w1p + (size_t)(jt * 16 + r16) * 128 + quad * 8;
#pragma unroll
        for (int kb = 0; kb < 4; kb++) {
            bf16x8 b = *(const bf16x8*)(wr + kb * 32);
            acc = __builtin_amdgcn_mfma_f32_16x16x32_bf16(a[kb], b, acc, 0, 0, 0);
        }
        int col = jt * 16 + r16;
        float bias = b1[col];
#pragma unroll
        for (int r = 0; r < 4; r++) {
            int row = base + quad * 4 + r;
            float v = fmaxf(acc[r] + bias, 0.f);
            out[(size_t)row * 64 + col] = f2bf(v);
        }
    }
}

// ---------------------------------------------------------------------------
// conv (CSR): out[d,:] = sum_{e in row d} h[src_e,:] * coef_e   (bf16 in/out, fp32 accum)
// wave per dst node, lane = feature.
__global__ __launch_bounds__(256) void conv_csr(const unsigned short* __restrict__ hin,
                                                const int* __restrict__ rowptr,
                                                const Rec* __restrict__ rec,
                                                unsigned short* __restrict__ out) {
    int d = (blockIdx.x * 256 + threadIdx.x) >> 6;
    if (d >= N_NODES) return;
    int lane = threadIdx.x & 63;
    int b = rowptr[d], e = rowptr[d + 1];
    float acc = 0.f;
    int i = b;
    for (; i + 2 <= e; i += 2) {  // 2-way unroll: independent gathers in flight
        Rec r0 = rec[i];
        Rec r1 = rec[i + 1];
        float v0 = bf2f(hin[(size_t)r0.s * 64 + lane]);
        float v1 = bf2f(hin[(size_t)r1.s * 64 + lane]);
        acc += v0 * r0.c + v1 * r1.c;
    }
    if (i < e) {
        Rec r = rec[i];
        acc += bf2f(hin[(size_t)r.s * 64 + lane]) * r.c;
    }
    out[(size_t)d * 64 + lane] = f2bf(acc);
}

// ---------------------------------------------------------------------------
// dense block: out = relu( [h,conv]@W^T + (h@Aa^T)*(h@Ab^T) )
// wave = 16-node tile; 10 MFMAs per 16x16 output tile; everything from global (L2-hot).
__global__ __launch_bounds__(256) void dense_mfma(const unsigned short* __restrict__ h,
                                                  const unsigned short* __restrict__ cv,
                                                  const unsigned short* __restrict__ wp,
                                                  const unsigned short* __restrict__ aap,
                                                  const unsigned short* __restrict__ abp,
                                                  unsigned short* __restrict__ outb,
                                                  float* __restrict__ outf,
                                                  int finalLayer) {
    int wave = (blockIdx.x * 256 + threadIdx.x) >> 6;
    if (wave >= NTILES) return;
    int lane = threadIdx.x & 63;
    int r16 = lane & 15, quad = lane >> 4;
    int base = wave * 16;

    const unsigned short* hr = h + (size_t)(base + r16) * 64 + quad * 8;
    const unsigned short* cr = cv + (size_t)(base + r16) * 64 + quad * 8;
    bf16x8 ha0 = *(const bf16x8*)(hr);
    bf16x8 ha1 = *(const bf16x8*)(hr + 32);
    bf16x8 ca0 = *(const bf16x8*)(cr);
    bf16x8 ca1 = *(const bf16x8*)(cr + 32);

#pragma unroll
    for (int jt = 0; jt < 4; jt++) {
        const unsigned short* wr = wp + (size_t)(jt * 16 + r16) * 128 + quad * 8;
        const unsigned short* ar = aap + (size_t)(jt * 16 + r16) * 64 + quad * 8;
        const unsigned short* br = abp + (size_t)(jt * 16 + r16) * 64 + quad * 8;
        f32x4 P = {0.f, 0.f, 0.f, 0.f};
        f32x4 Q = {0.f, 0.f, 0.f, 0.f};
        f32x4 R = {0.f, 0.f, 0.f, 0.f};
        // P: k 0..63 vs h, k 64..127 vs conv  (cat = [h, conv])
        P = __builtin_amdgcn_mfma_f32_16x16x32_bf16(ha0, *(const bf16x8*)(wr), P, 0, 0, 0);
        P = __builtin_amdgcn_mfma_f32_16x16x32_bf16(ha1, *(const bf16x8*)(wr + 32), P, 0, 0, 0);
        P = __builtin_amdgcn_mfma_f32_16x16x32_bf16(ca0, *(const bf16x8*)(wr + 64), P, 0, 0, 0);
        P = __builtin_amdgcn_mfma_f32_16x16x32_bf16(ca1, *(const bf16x8*)(wr + 96), P, 0, 0, 0);
        Q = __builtin_amdgcn_mfma_f32_16x16x32_bf16(ha0, *(const bf16x8*)(ar), Q, 0, 0, 0);
        Q = __builtin_amdgcn_mfma_f32_16x16x32_bf16(ha1, *(const bf16x8*)(ar + 32), Q, 0, 0, 0);
        R = __builtin_amdgcn_mfma_f32_16x16x32_bf16(ha0, *(const bf16x8*)(br), R, 0, 0, 0);
        R = __builtin_amdgcn_mfma_f32_16x16x32_bf16(ha1, *(const bf16x8*)(br + 32), R, 0, 0, 0);
        int col = jt * 16 + r16;
#pragma unroll
        for (int r = 0; r < 4; r++) {
            int row = base + quad * 4 + r;
            float v = fmaxf(P[r] + Q[r] * R[r], 0.f);
            if (finalLayer) outf[(size_t)row * 64 + col] = v;
            else            outb[(size_t)row * 64 + col] = f2bf(v);
        }
    }
}

// ---------------------------------------------------------------------------
extern "C" void kernel_launch(void* const* d_in, const int* in_sizes, int n_in,
                              void* d_out, int out_size, void* d_ws, size_t ws_size,
                              hipStream_t stream) {
    const float* x = (const float*)d_in[0];
    const int* edges = (const int*)d_in[1];
    const float* W1 = (const float*)d_in[2];
    const float* b1 = (const float*)d_in[3];
    const float* W2 = (const float*)d_in[4];
    const float* A2a = (const float*)d_in[5];
    const float* A2b = (const float*)d_in[6];
    const float* W3 = (const float*)d_in[7];
    const float* A3a = (const float*)d_in[8];
    const float* A3b = (const float*)d_in[9];
    const float* W4 = (const float*)d_in[10];
    const float* A4a = (const float*)d_in[11];
    const float* A4b = (const float*)d_in[12];
    float* out = (float*)d_out;

    const int* src = edges;
    const int* dst = edges + N_EDGES;

    // ---- workspace carve-up (256B aligned regions) ----
    char* p = (char*)d_ws;
    auto alloc = [&](size_t bytes) {
        char* r = p;
        p += (bytes + 255) & ~(size_t)255;
        return r;
    };
    int* degi            = (int*)alloc(N_NODES * 4);
    int* incl            = (int*)alloc(N_NODES * 4);
    int* partial         = (int*)alloc(256 * 4);
    float* isq           = (float*)alloc(N_NODES * 4);
    int* rowptr          = (int*)alloc((N_NODES + 1) * 4);
    int* cursor          = (int*)alloc(N_NODES * 4);
    Rec* rec             = (Rec*)alloc(N_EDGES * 8);
    unsigned short* wpAll= (unsigned short*)alloc(W_TOTAL * 2);
    unsigned short* bufA = (unsigned short*)alloc((size_t)N_NODES * 64 * 2);
    unsigned short* bufB = (unsigned short*)alloc((size_t)N_NODES * 64 * 2);
    unsigned short* bufC = (unsigned short*)alloc((size_t)N_NODES * 64 * 2);

    const unsigned short* W1p  = wpAll;
    const unsigned short* W2p  = wpAll + 8192;
    const unsigned short* A2ap = wpAll + 16384;
    const unsigned short* A2bp = wpAll + 20480;
    const unsigned short* W3p  = wpAll + 24576;
    const unsigned short* A3ap = wpAll + 32768;
    const unsigned short* A3bp = wpAll + 36864;
    const unsigned short* W4p  = wpAll + 40960;
    const unsigned short* A4ap = wpAll + 49152;
    const unsigned short* A4bp = wpAll + 53248;

    const int EB = (N_EDGES + 255) / 256;   // 3125
    const int TB = (NTILES + 3) / 4;        // 782 blocks (4 waves/block)
    const int CB = (N_NODES + 3) / 4;       // 12500 blocks (4 dst-waves/block)

    // ---- CSR build (edges fixed; one build serves all 3 convs) ----
    hipMemsetAsync(degi, 0, N_NODES * 4, stream);
    count_kernel<<<EB, 256, 0, stream>>>(dst, degi);
    scan1_kernel<<<SCAN_NB, 256, 0, stream>>>(degi, incl, partial, isq);
    scan2_kernel<<<1, 256, 0, stream>>>(partial);
    scan3_kernel<<<SCAN_NB, 256, 0, stream>>>(incl, partial, degi, rowptr, cursor);
    scatter_kernel<<<EB, 256, 0, stream>>>(src, dst, isq, cursor, rec);

    // ---- weights -> bf16 ----
    pack_w_kernel<<<(W_TOTAL + 255) / 256, 256, 0, stream>>>(W1, W2, A2a, A2b, W3, A3a, A3b,
                                                             W4, A4a, A4b, wpAll);

    // ---- layer 1 ----
    layer1_mfma<<<TB, 256, 0, stream>>>(x, W1p, b1, bufA);

    // ---- block 2: bufA -> bufB ----
    conv_csr<<<CB, 256, 0, stream>>>(bufA, rowptr, rec, bufC);
    dense_mfma<<<TB, 256, 0, stream>>>(bufA, bufC, W2p, A2ap, A2bp, bufB, nullptr, 0);

    // ---- block 3: bufB -> bufA ----
    conv_csr<<<CB, 256, 0, stream>>>(bufB, rowptr, rec, bufC);
    dense_mfma<<<TB, 256, 0, stream>>>(bufB, bufC, W3p, A3ap, A3bp, bufA, nullptr, 0);

    // ---- block 4: bufA -> d_out (fp32) ----
    conv_csr<<<CB, 256, 0, stream>>>(bufA, rowptr, rec, bufC);
    dense_mfma<<<TB, 256, 0, stream>>>(bufA, bufC, W4p, A4ap, A4bp, nullptr, out, 1);
}

// Round 4
// 314.031 us; speedup vs baseline: 3.7560x; 1.2119x over previous
//
#include <hip/hip_runtime.h>
#include <hip/hip_bf16.h>
#include <hip/hip_fp16.h>

#define N_NODES 50000
#define N_EDGES 800000
#define NTILES 3125        // N_NODES / 16
#define SCAN_NB 196        // ceil(N_NODES / 256)
#define W_TOTAL 57344      // packed bf16 weight elements
#define EB 3125            // edge blocks (N_EDGES/256)
#define WB 224             // weight-pack blocks
#define SRC_PAD 512        // sentinel tail on srcA

typedef __attribute__((ext_vector_type(8))) short bf16x8;   // MFMA A/B frag
typedef __attribute__((ext_vector_type(4))) float f32x4;    // MFMA C/D frag

__device__ inline float bf2f(unsigned short u) {
    return __uint_as_float(((unsigned int)u) << 16);
}
__device__ inline unsigned short f2bf(float f) {  // round-to-nearest-even
    unsigned int x = __float_as_uint(f);
    unsigned int r = (x + 0x7FFF + ((x >> 16) & 1)) >> 16;
    return (unsigned short)r;
}
__device__ inline float2 h2f2(unsigned int u) {   // packed half2 -> float2
    __half2 h = *(__half2*)&u;
    return make_float2(__low2float(h), __high2float(h));
}

// ---------------------------------------------------------------------------
// fused: degree count (blocks [0,EB)) + weight bf16 pack (blocks [EB,EB+WB))
__global__ __launch_bounds__(256) void count_pack_kernel(
    const int* __restrict__ dst, int* __restrict__ degi,
    const float* W1, const float* W2, const float* A2a, const float* A2b,
    const float* W3, const float* A3a, const float* A3b,
    const float* W4, const float* A4a, const float* A4b,
    unsigned short* __restrict__ wp) {
    if (blockIdx.x < EB) {
        int e = blockIdx.x * 256 + threadIdx.x;
        if (e < N_EDGES) atomicAdd(&degi[dst[e]], 1);
    } else {
        int i = (blockIdx.x - EB) * 256 + threadIdx.x;
        if (i >= W_TOTAL) return;
        float v;
        if (i < 8192)       v = W1[i];
        else if (i < 16384) v = W2[i - 8192];
        else if (i < 20480) v = A2a[i - 16384];
        else if (i < 24576) v = A2b[i - 20480];
        else if (i < 32768) v = W3[i - 24576];
        else if (i < 36864) v = A3a[i - 32768];
        else if (i < 40960) v = A3b[i - 36864];
        else if (i < 49152) v = W4[i - 40960];
        else if (i < 53248) v = A4a[i - 49152];
        else                v = A4b[i - 53248];
        wp[i] = f2bf(v);
    }
}

// scan phase 1: per-256-chunk inclusive scan + chunk totals; also isq = rsqrt(max(deg,1))
__global__ __launch_bounds__(256) void scan1_kernel(const int* __restrict__ degi,
                                                    int* __restrict__ incl,
                                                    int* __restrict__ partial,
                                                    float* __restrict__ isq) {
    __shared__ int s[256];
    int gid = blockIdx.x * 256 + threadIdx.x;
    int v = (gid < N_NODES) ? degi[gid] : 0;
    if (gid < N_NODES) isq[gid] = rsqrtf(fmaxf((float)v, 1.0f));
    s[threadIdx.x] = v;
    __syncthreads();
    for (int off = 1; off < 256; off <<= 1) {
        int t = (threadIdx.x >= off) ? s[threadIdx.x - off] : 0;
        __syncthreads();
        s[threadIdx.x] += t;
        __syncthreads();
    }
    if (gid < N_NODES) incl[gid] = s[threadIdx.x];
    if (threadIdx.x == 255) partial[blockIdx.x] = s[255];
}

// scan phase 2 (one block): exclusive scan of chunk totals + srcA sentinel init
__global__ __launch_bounds__(256) void scan2_kernel(int* __restrict__ partial,
                                                    int* __restrict__ srcA) {
    __shared__ int s[256];
    int v = (threadIdx.x < SCAN_NB) ? partial[threadIdx.x] : 0;
    s[threadIdx.x] = v;
    __syncthreads();
    for (int off = 1; off < 256; off <<= 1) {
        int t = (threadIdx.x >= off) ? s[threadIdx.x - off] : 0;
        __syncthreads();
        s[threadIdx.x] += t;
        __syncthreads();
    }
    if (threadIdx.x < SCAN_NB) partial[threadIdx.x] = s[threadIdx.x] - v;  // exclusive
    srcA[N_EDGES + threadIdx.x] = 0;            // sentinel tail (node 0)
    srcA[N_EDGES + 256 + threadIdx.x] = 0;
}

// scan phase 3: rowptr (exclusive) + cursor copy
__global__ __launch_bounds__(256) void scan3_kernel(const int* __restrict__ incl,
                                                    const int* __restrict__ partial,
                                                    const int* __restrict__ degi,
                                                    int* __restrict__ rowptr,
                                                    int* __restrict__ cursor) {
    int gid = blockIdx.x * 256 + threadIdx.x;
    if (gid < N_NODES) {
        int excl = partial[blockIdx.x] + incl[gid] - degi[gid];
        rowptr[gid] = excl;
        cursor[gid] = excl;
    }
    if (gid == 0) rowptr[N_NODES] = N_EDGES;
}

// scatter edges into CSR order: 4-byte records (src only)
__global__ __launch_bounds__(256) void scatter_kernel(const int* __restrict__ src,
                                                      const int* __restrict__ dst,
                                                      int* __restrict__ cursor,
                                                      int* __restrict__ srcA) {
    int e = blockIdx.x * 256 + threadIdx.x;
    if (e < N_EDGES) {
        int d = dst[e];
        int pos = atomicAdd(&cursor[d], 1);
        srcA[pos] = src[e];
    }
}

// ---------------------------------------------------------------------------
// layer1: h = relu(x @ W1^T + b1) via 16x16x32 bf16 MFMA; epilogue also writes
// hs = isq[row]*h as fp16 (pre-scaled rows for the conv gather).
__global__ __launch_bounds__(256) void layer1_mfma(const float* __restrict__ x,
                                                   const unsigned short* __restrict__ w1p,
                                                   const float* __restrict__ b1,
                                                   const float* __restrict__ isq,
                                                   unsigned short* __restrict__ outh,
                                                   __half* __restrict__ outs) {
    int wave = (blockIdx.x * 256 + threadIdx.x) >> 6;
    if (wave >= NTILES) return;
    int lane = threadIdx.x & 63;
    int r16 = lane & 15, quad = lane >> 4;
    int base = wave * 16;

    bf16x8 a[4];
    const float* xr = x + (size_t)(base + r16) * 128 + quad * 8;
#pragma unroll
    for (int kb = 0; kb < 4; kb++) {
        float4 f0 = *(const float4*)(xr + kb * 32);
        float4 f1 = *(const float4*)(xr + kb * 32 + 4);
        bf16x8 v;
        v[0] = (short)f2bf(f0.x); v[1] = (short)f2bf(f0.y);
        v[2] = (short)f2bf(f0.z); v[3] = (short)f2bf(f0.w);
        v[4] = (short)f2bf(f1.x); v[5] = (short)f2bf(f1.y);
        v[6] = (short)f2bf(f1.z); v[7] = (short)f2bf(f1.w);
        a[kb] = v;
    }

    float isq4[4];
#pragma unroll
    for (int r = 0; r < 4; r++) isq4[r] = isq[base + quad * 4 + r];

#pragma unroll
    for (int jt = 0; jt < 4; jt++) {
        f32x4 acc = {0.f, 0.f, 0.f, 0.f};
        const unsigned short* wr = w1p + (size_t)(jt * 16 + r16) * 128 + quad * 8;
#pragma unroll
        for (int kb = 0; kb < 4; kb++) {
            bf16x8 b = *(const bf16x8*)(wr + kb * 32);
            acc = __builtin_amdgcn_mfma_f32_16x16x32_bf16(a[kb], b, acc, 0, 0, 0);
        }
        int col = jt * 16 + r16;
        float bias = b1[col];
#pragma unroll
        for (int r = 0; r < 4; r++) {
            int row = base + quad * 4 + r;
            float v = fmaxf(acc[r] + bias, 0.f);
            outh[(size_t)row * 64 + col] = f2bf(v);
            outs[(size_t)row * 64 + col] = __float2half(v * isq4[r]);
        }
    }
}

// ---------------------------------------------------------------------------
// conv (CSR, 4 rows/wave): out[d,:] = isq[d] * sum_{e in row d} hs[src_e,:]
// quarter-wave per dst row; lane covers 4 feats (ushort4 = one 8B gather);
// one gather instruction serves 4 edges. Sentinel-padded srcA keeps all loads
// unconditional; accumulate is masked.
__global__ __launch_bounds__(256) void conv_csr4(const __half* __restrict__ hs,
                                                 const int* __restrict__ rowptr,
                                                 const int* __restrict__ srcA,
                                                 const float* __restrict__ isq,
                                                 unsigned short* __restrict__ out) {
    int wave = (blockIdx.x * 256 + threadIdx.x) >> 6;
    if (wave >= N_NODES / 4) return;
    int lane = threadIdx.x & 63;
    int q = lane >> 4, fl = lane & 15;
    int d = wave * 4 + q;
    int b = rowptr[d];
    int cnt = rowptr[d + 1] - b;
    int m = cnt;
    m = max(m, __shfl_xor(m, 16));
    m = max(m, __shfl_xor(m, 32));

    const unsigned int* hsp = (const unsigned int*)hs;  // 1 uint = 2 halves
    float a0 = 0.f, a1 = 0.f, a2 = 0.f, a3 = 0.f;
    for (int i = 0; i < m; i += 4) {
#pragma unroll
        for (int u = 0; u < 4; u++) {
            int j = i + u;
            int s = srcA[b + j];                       // sentinel-safe
            uint2 raw = *(const uint2*)(hsp + ((size_t)s << 5) + (fl << 1));
            bool ok = j < cnt;
            unsigned int r0 = ok ? raw.x : 0u;
            unsigned int r1 = ok ? raw.y : 0u;
            float2 f0 = h2f2(r0), f1 = h2f2(r1);
            a0 += f0.x; a1 += f0.y; a2 += f1.x; a3 += f1.y;
        }
    }
    float sc = isq[d];
    ushort4 o;
    o.x = f2bf(a0 * sc); o.y = f2bf(a1 * sc);
    o.z = f2bf(a2 * sc); o.w = f2bf(a3 * sc);
    *(ushort4*)(out + (size_t)d * 64 + fl * 4) = o;
}

// ---------------------------------------------------------------------------
// dense block: out = relu( [h,conv]@W^T + (h@Aa^T)*(h@Ab^T) )
// epilogue writes h (bf16) + hs = isq*h (fp16) unless final layer (fp32 out).
__global__ __launch_bounds__(256) void dense_mfma(const unsigned short* __restrict__ h,
                                                  const unsigned short* __restrict__ cv,
                                                  const unsigned short* __restrict__ wp,
                                                  const unsigned short* __restrict__ aap,
                                                  const unsigned short* __restrict__ abp,
                                                  const float* __restrict__ isq,
                                                  unsigned short* __restrict__ outh,
                                                  __half* __restrict__ outs,
                                                  float* __restrict__ outf,
                                                  int finalLayer) {
    int wave = (blockIdx.x * 256 + threadIdx.x) >> 6;
    if (wave >= NTILES) return;
    int lane = threadIdx.x & 63;
    int r16 = lane & 15, quad = lane >> 4;
    int base = wave * 16;

    const unsigned short* hr = h + (size_t)(base + r16) * 64 + quad * 8;
    const unsigned short* cr = cv + (size_t)(base + r16) * 64 + quad * 8;
    bf16x8 ha0 = *(const bf16x8*)(hr);
    bf16x8 ha1 = *(const bf16x8*)(hr + 32);
    bf16x8 ca0 = *(const bf16x8*)(cr);
    bf16x8 ca1 = *(const bf16x8*)(cr + 32);

    float isq4[4];
    if (!finalLayer) {
#pragma unroll
        for (int r = 0; r < 4; r++) isq4[r] = isq[base + quad * 4 + r];
    }

#pragma unroll
    for (int jt = 0; jt < 4; jt++) {
        const unsigned short* wr = wp + (size_t)(jt * 16 + r16) * 128 + quad * 8;
        const unsigned short* ar = aap + (size_t)(jt * 16 + r16) * 64 + quad * 8;
        const unsigned short* br = abp + (size_t)(jt * 16 + r16) * 64 + quad * 8;
        f32x4 P = {0.f, 0.f, 0.f, 0.f};
        f32x4 Q = {0.f, 0.f, 0.f, 0.f};
        f32x4 R = {0.f, 0.f, 0.f, 0.f};
        P = __builtin_amdgcn_mfma_f32_16x16x32_bf16(ha0, *(const bf16x8*)(wr), P, 0, 0, 0);
        P = __builtin_amdgcn_mfma_f32_16x16x32_bf16(ha1, *(const bf16x8*)(wr + 32), P, 0, 0, 0);
        P = __builtin_amdgcn_mfma_f32_16x16x32_bf16(ca0, *(const bf16x8*)(wr + 64), P, 0, 0, 0);
        P = __builtin_amdgcn_mfma_f32_16x16x32_bf16(ca1, *(const bf16x8*)(wr + 96), P, 0, 0, 0);
        Q = __builtin_amdgcn_mfma_f32_16x16x32_bf16(ha0, *(const bf16x8*)(ar), Q, 0, 0, 0);
        Q = __builtin_amdgcn_mfma_f32_16x16x32_bf16(ha1, *(const bf16x8*)(ar + 32), Q, 0, 0, 0);
        R = __builtin_amdgcn_mfma_f32_16x16x32_bf16(ha0, *(const bf16x8*)(br), R, 0, 0, 0);
        R = __builtin_amdgcn_mfma_f32_16x16x32_bf16(ha1, *(const bf16x8*)(br + 32), R, 0, 0, 0);
        int col = jt * 16 + r16;
#pragma unroll
        for (int r = 0; r < 4; r++) {
            int row = base + quad * 4 + r;
            float v = fmaxf(P[r] + Q[r] * R[r], 0.f);
            if (finalLayer) {
                outf[(size_t)row * 64 + col] = v;
            } else {
                outh[(size_t)row * 64 + col] = f2bf(v);
                outs[(size_t)row * 64 + col] = __float2half(v * isq4[r]);
            }
        }
    }
}

// ---------------------------------------------------------------------------
extern "C" void kernel_launch(void* const* d_in, const int* in_sizes, int n_in,
                              void* d_out, int out_size, void* d_ws, size_t ws_size,
                              hipStream_t stream) {
    const float* x = (const float*)d_in[0];
    const int* edges = (const int*)d_in[1];
    const float* W1 = (const float*)d_in[2];
    const float* b1 = (const float*)d_in[3];
    const float* W2 = (const float*)d_in[4];
    const float* A2a = (const float*)d_in[5];
    const float* A2b = (const float*)d_in[6];
    const float* W3 = (const float*)d_in[7];
    const float* A3a = (const float*)d_in[8];
    const float* A3b = (const float*)d_in[9];
    const float* W4 = (const float*)d_in[10];
    const float* A4a = (const float*)d_in[11];
    const float* A4b = (const float*)d_in[12];
    float* out = (float*)d_out;

    const int* src = edges;
    const int* dst = edges + N_EDGES;

    char* p = (char*)d_ws;
    auto alloc = [&](size_t bytes) {
        char* r = p;
        p += (bytes + 255) & ~(size_t)255;
        return r;
    };
    int* degi             = (int*)alloc(N_NODES * 4);
    int* incl             = (int*)alloc(N_NODES * 4);
    int* partial          = (int*)alloc(256 * 4);
    float* isq            = (float*)alloc(N_NODES * 4);
    int* rowptr           = (int*)alloc((N_NODES + 1) * 4);
    int* cursor           = (int*)alloc(N_NODES * 4);
    int* srcA             = (int*)alloc((N_EDGES + SRC_PAD) * 4);
    unsigned short* wpAll = (unsigned short*)alloc(W_TOTAL * 2);
    unsigned short* Ah    = (unsigned short*)alloc((size_t)N_NODES * 64 * 2);
    __half* As            = (__half*)alloc((size_t)N_NODES * 64 * 2);
    unsigned short* Bh    = (unsigned short*)alloc((size_t)N_NODES * 64 * 2);
    unsigned short* C     = (unsigned short*)alloc((size_t)N_NODES * 64 * 2);

    const unsigned short* W1p  = wpAll;
    const unsigned short* W2p  = wpAll + 8192;
    const unsigned short* A2ap = wpAll + 16384;
    const unsigned short* A2bp = wpAll + 20480;
    const unsigned short* W3p  = wpAll + 24576;
    const unsigned short* A3ap = wpAll + 32768;
    const unsigned short* A3bp = wpAll + 36864;
    const unsigned short* W4p  = wpAll + 40960;
    const unsigned short* A4ap = wpAll + 49152;
    const unsigned short* A4bp = wpAll + 53248;

    const int TB = (NTILES + 3) / 4;          // dense/layer1 blocks (4 waves ea.)
    const int CB = N_NODES / 4 / 4;           // conv blocks: 12500 waves / 4

    // ---- CSR build + weight pack ----
    hipMemsetAsync(degi, 0, N_NODES * 4, stream);
    count_pack_kernel<<<EB + WB, 256, 0, stream>>>(dst, degi, W1, W2, A2a, A2b, W3, A3a,
                                                   A3b, W4, A4a, A4b, wpAll);
    scan1_kernel<<<SCAN_NB, 256, 0, stream>>>(degi, incl, partial, isq);
    scan2_kernel<<<1, 256, 0, stream>>>(partial, srcA);
    scan3_kernel<<<SCAN_NB, 256, 0, stream>>>(incl, partial, degi, rowptr, cursor);
    scatter_kernel<<<EB, 256, 0, stream>>>(src, dst, cursor, srcA);

    // ---- layer 1: x -> Ah (bf16) + As (fp16, pre-scaled) ----
    layer1_mfma<<<TB, 256, 0, stream>>>(x, W1p, b1, isq, Ah, As);

    // ---- block 2 ----
    conv_csr4<<<CB, 256, 0, stream>>>(As, rowptr, srcA, isq, C);
    dense_mfma<<<TB, 256, 0, stream>>>(Ah, C, W2p, A2ap, A2bp, isq, Bh, As, nullptr, 0);

    // ---- block 3 ----
    conv_csr4<<<CB, 256, 0, stream>>>(As, rowptr, srcA, isq, C);
    dense_mfma<<<TB, 256, 0, stream>>>(Bh, C, W3p, A3ap, A3bp, isq, Ah, As, nullptr, 0);

    // ---- block 4 -> d_out (fp32) ----
    conv_csr4<<<CB, 256, 0, stream>>>(As, rowptr, srcA, isq, C);
    dense_mfma<<<TB, 256, 0, stream>>>(Ah, C, W4p, A4ap, A4bp, isq, nullptr, nullptr, out, 1);
}